// Round 1
// baseline (409.486 us; speedup 1.0000x reference)
//
#include <hip/hip_runtime.h>
#include <cmath>

// (B, N, F_IN, M, U) = (2, 2048, 128, 8, 64)
#define N_ 2048
#define F_ 128
#define M_ 8
#define U_ 64

typedef _Float16 f16;
typedef _Float16 f16x2 __attribute__((ext_vector_type(2)));
typedef _Float16 f16x8 __attribute__((ext_vector_type(8)));
typedef float f32x4 __attribute__((ext_vector_type(4)));

#define BK 32   // K-chunk (j) per stage
#define RS 40   // LDS row stride in fp16 (BK + 8 pad; 80 B, 16-B aligned)
#define NCH (N_ / BK)  // 64 chunks

// -------------------------------------------------------------------------
// k_beta: beta[b][n][u] = sum_f seq[b,n,f] * ew[f,u], computed fp32, stored
// SPLIT-fp16 TRANSPOSED: bh/bl[b][u][n] (k-major for k_main's B fragments).
// hi = rn(v), lo = rn(v - hi) -> hi+lo == v to ~2^-24 rel.
// grid 256, block 256. Scalar b16 stores are scattered but beta is tiny.
// -------------------------------------------------------------------------
__global__ __launch_bounds__(256) void k_beta(const float* __restrict__ seq,
                                              const float* __restrict__ ew,
                                              f16* __restrict__ bh,
                                              f16* __restrict__ bl) {
  __shared__ float st[16 * 132];
  const int t    = threadIdx.x;
  const int lane = t & 63;
  const int wv   = t >> 6;
  const int row0 = blockIdx.x * 16;
#pragma unroll
  for (int k = 0; k < 2; ++k) {
    int id = t + k * 256;
    int r = id >> 5, f4 = id & 31;
    float4 v = *(const float4*)(seq + (size_t)(row0 + r) * F_ + f4 * 4);
    *(float4*)&st[r * 132 + f4 * 4] = v;
  }
  __syncthreads();
  const int r0 = wv * 4;
  float acc[4] = {0.f, 0.f, 0.f, 0.f};
#pragma unroll 8
  for (int f = 0; f < F_; ++f) {
    float e = ew[f * U_ + lane];
#pragma unroll
    for (int r = 0; r < 4; ++r)
      acc[r] = fmaf(st[(r0 + r) * 132 + f], e, acc[r]);
  }
#pragma unroll
  for (int r = 0; r < 4; ++r) {
    int row = row0 + r0 + r;
    int b = row >> 11, n = row & (N_ - 1);
    float v = acc[r];
    f16 h = (f16)v;
    f16 l = (f16)(v - (float)h);
    size_t idx = ((size_t)(b * U_ + lane)) * N_ + n;  // [b][u][n]
    bh[idx] = h;
    bl[idx] = l;
  }
}

// -------------------------------------------------------------------------
// k_alpha: out[b,n,m,u] = sum_f seq[b,n,f]*vw[f,m,u] (fp32 pre-activation
// into d_out; k_main adds graph term + sigmoid). Unchanged.
// -------------------------------------------------------------------------
__global__ __launch_bounds__(256, 2) void k_alpha(const float* __restrict__ seq,
                                                  const float* __restrict__ vw,
                                                  float* __restrict__ out) {
  __shared__ float ss[8 * 128];
  const int t    = threadIdx.x;
  const int q    = t & 15;
  const int g    = t >> 4;
  const int r    = g & 7;
  const int mh   = g >> 3;
  const int row0 = blockIdx.x * 8;
  {
    float4 v = *(const float4*)(seq + (size_t)row0 * F_ + t * 4);
    *(float4*)&ss[t * 4] = v;
  }
  __syncthreads();
  float acc[4][4] = {};
  const float* wbase = vw + mh * 4 * 64 + q * 4;
#pragma unroll 4
  for (int f = 0; f < F_; ++f) {
    float s = ss[r * F_ + f];
    const float* wf = wbase + (size_t)f * 512;
#pragma unroll
    for (int mm = 0; mm < 4; ++mm) {
      float4 wv = *(const float4*)(wf + mm * 64);
      acc[mm][0] = fmaf(s, wv.x, acc[mm][0]);
      acc[mm][1] = fmaf(s, wv.y, acc[mm][1]);
      acc[mm][2] = fmaf(s, wv.z, acc[mm][2]);
      acc[mm][3] = fmaf(s, wv.w, acc[mm][3]);
    }
  }
  float* o = out + (size_t)(row0 + r) * 512 + mh * 4 * 64 + q * 4;
#pragma unroll
  for (int mm = 0; mm < 4; ++mm) {
    float4 res;
    res.x = acc[mm][0]; res.y = acc[mm][1];
    res.z = acc[mm][2]; res.w = acc[mm][3];
    *(float4*)(o + mm * 64) = res;
  }
}

// -------------------------------------------------------------------------
// k_main v6 (MFMA, no-drain pipeline): per batch,
// C[r=i*8+m][u] = sum_j A[r][j]*B[j][u]; A = graph slice (fp32 -> split
// fp16 hi/lo on the fly), B = split-fp16 beta (k-major from k_beta).
// mfma_f32_16x16x32_f16, 3 MFMA/tile (hi*hi + lo*hi + hi*lo).
//
// v6 change: __syncthreads() emits s_waitcnt vmcnt(0) before s_barrier,
// draining ALL prefetch loads every chunk -> per-chunk full-latency
// serialization (measured ~0.7 TB/s, 11% of HBM). Replace with raw
// s_barrier + lgkmcnt(0) only (ds-write visibility); issue LOADC before
// WRITEC (two register sets) so the consuming wait is a COUNTED
// vmcnt(4), never 0, and graph loads stay in flight across barriers.
// Tail chunk-pairs are PEELED (no conditional loads in the steady loop:
// a guarded LOADC would make the compiler's waitcnt meet conservative ->
// vmcnt(0) at the merge, reintroducing the drain).
//
// Layouts (HW-verified facts): A-frag A[m=lane&15][k=(lane>>4)*8+j],
// B-frag B[k=(lane>>4)*8+j][n=lane&15], C/D col=lane&15,
// row=(lane>>4)*4+reg. LDS row stride RS=40 fp16 -> b128 frag reads at
// baseline rate; staging writes <=2-way (free). HBM floor: 268 MB /
// 6.3 TB/s = 43 us. Grid 512 = 2 blocks/CU, 8 waves/CU.
// -------------------------------------------------------------------------
__global__ __launch_bounds__(256, 2) void k_main(const float* __restrict__ graph,
                                                 const f16* __restrict__ betah,
                                                 const f16* __restrict__ betal,
                                                 float* __restrict__ out) {
  __shared__ f16 Ah[2][64 * RS];
  __shared__ f16 Al[2][64 * RS];
  __shared__ f16 Bh[2][64 * RS];
  __shared__ f16 Bl[2][64 * RS];

  const int t    = threadIdx.x;
  const int w    = t >> 6;
  const int lane = t & 63;
  const int l15  = lane & 15;
  const int quad = lane >> 4;

  const int bx = blockIdx.x;
  const int b  = bx >> 8;
  const int rb = bx & 255;        // 64-row tile; i0 = rb*8

  // staging decode: A: thread -> (i_loc, j-pair, m-half); B: (u-row, j-part)
  const int iA = t >> 5;          // 0..7
  const int r5 = t & 31;
  const int jp = r5 >> 1;         // 0..15
  const int mh = r5 & 1;          // 0..1
  const int uB = t >> 2;          // 0..63
  const int pB = t & 3;           // 0..3

  const float* gA = graph + ((size_t)(b * N_ + rb * 8 + iA)) * (N_ * M_) + mh * 4;
  const f16* bhp = betah + ((size_t)(b * U_ + uB)) * N_ + pB * 8;
  const f16* blp = betal + ((size_t)(b * U_ + uB)) * N_ + pB * 8;

  f32x4 acc[4] = {f32x4{0.f, 0.f, 0.f, 0.f}, f32x4{0.f, 0.f, 0.f, 0.f},
                  f32x4{0.f, 0.f, 0.f, 0.f}, f32x4{0.f, 0.f, 0.f, 0.f}};

  // two register prefetch sets (S = 0/1)
  float4 ra0_0, ra1_0; uint4 rbh_0, rbl_0;
  float4 ra0_1, ra1_1; uint4 rbh_1, rbl_1;

#define LOADC(c, S)                                                       \
  do {                                                                    \
    const float* g_ = gA + (size_t)((c) * BK + jp * 2) * M_;              \
    ra0_##S = *(const float4*)g_;                                         \
    ra1_##S = *(const float4*)(g_ + M_);                                  \
    rbh_##S = *(const uint4*)(bhp + (c) * BK);                            \
    rbl_##S = *(const uint4*)(blp + (c) * BK);                            \
  } while (0)

#define WRITEC(buf, S)                                                    \
  do {                                                                    \
    float g0s[4] = {ra0_##S.x, ra0_##S.y, ra0_##S.z, ra0_##S.w};          \
    float g1s[4] = {ra1_##S.x, ra1_##S.y, ra1_##S.z, ra1_##S.w};          \
    _Pragma("unroll") for (int mw = 0; mw < 4; ++mw) {                    \
      float g0 = g0s[mw], g1 = g1s[mw];                                   \
      f16 h0 = (f16)g0, h1 = (f16)g1;                                     \
      f16 l0 = (f16)(g0 - (float)h0), l1 = (f16)(g1 - (float)h1);         \
      int r_ = iA * 8 + mh * 4 + mw;                                      \
      f16x2 hv; hv[0] = h0; hv[1] = h1;                                   \
      f16x2 lv; lv[0] = l0; lv[1] = l1;                                   \
      *(f16x2*)&Ah[buf][r_ * RS + jp * 2] = hv;                           \
      *(f16x2*)&Al[buf][r_ * RS + jp * 2] = lv;                           \
    }                                                                     \
    *(uint4*)&Bh[buf][uB * RS + pB * 8] = rbh_##S;                        \
    *(uint4*)&Bl[buf][uB * RS + pB * 8] = rbl_##S;                        \
  } while (0)

#define COMPUTE(buf)                                                      \
  do {                                                                    \
    const int ab_ = (w * 16 + l15) * RS + quad * 8;                       \
    f16x8 ah = *(const f16x8*)&Ah[buf][ab_];                              \
    f16x8 al = *(const f16x8*)&Al[buf][ab_];                              \
    _Pragma("unroll") for (int ut = 0; ut < 4; ++ut) {                    \
      const int bb_ = (ut * 16 + l15) * RS + quad * 8;                    \
      f16x8 bhf = *(const f16x8*)&Bh[buf][bb_];                           \
      f16x8 blf = *(const f16x8*)&Bl[buf][bb_];                           \
      acc[ut] = __builtin_amdgcn_mfma_f32_16x16x32_f16(ah, bhf, acc[ut], 0, 0, 0); \
      acc[ut] = __builtin_amdgcn_mfma_f32_16x16x32_f16(al, bhf, acc[ut], 0, 0, 0); \
      acc[ut] = __builtin_amdgcn_mfma_f32_16x16x32_f16(ah, blf, acc[ut], 0, 0, 0); \
    }                                                                     \
  } while (0)

// raw barrier: each wave drains its OWN ds traffic (lgkmcnt), NOT vmcnt —
// global prefetch loads stay in flight across the barrier.
#define BAR()                                                             \
  do {                                                                    \
    asm volatile("s_waitcnt lgkmcnt(0)" ::: "memory");                    \
    __builtin_amdgcn_s_barrier();                                         \
    asm volatile("" ::: "memory");                                        \
  } while (0)

  // prologue: buf0 <- chunk0 (one full-latency wait, only here);
  // set1 <- chunk1 stays in flight across the first compute.
  LOADC(0, 0);
  WRITEC(0, 0);
  LOADC(1, 1);
  BAR();

  // steady state: chunks 0..59, NO conditionals -> counted vmcnt(4) waits.
  // invariants entering pair cc: buf0 = chunk cc, set1 = chunk cc+1 (in
  // flight), set0 free.
  for (int cc = 0; cc < NCH - 4; cc += 2) {
    COMPUTE(0);                   // chunk cc
    LOADC(cc + 2, 0);             // issue BEFORE consuming set1
    WRITEC(1, 1);                 // buf1 <- chunk cc+1 (vmcnt(4): waits old set only)
    BAR();
    COMPUTE(1);                   // chunk cc+1
    LOADC(cc + 3, 1);
    WRITEC(0, 0);                 // buf0 <- chunk cc+2
    BAR();
  }

  // peeled tail: chunks 60..63 (loads 62, 63 issued here; no guards)
  COMPUTE(0);                     // chunk 60
  LOADC(NCH - 2, 0);              // 62
  WRITEC(1, 1);                   // buf1 <- chunk 61
  BAR();
  COMPUTE(1);                     // chunk 61
  LOADC(NCH - 1, 1);              // 63
  WRITEC(0, 0);                   // buf0 <- chunk 62
  BAR();
  COMPUTE(0);                     // chunk 62
  WRITEC(1, 1);                   // buf1 <- chunk 63 (vmcnt(0) once, tail only)
  BAR();
  COMPUTE(1);                     // chunk 63

  // Epilogue: C row = rb*64 + w*16 + quad*4 + reg, col u = ut*16 + l15.
  const int rowbase = rb * 64 + w * 16 + quad * 4;
#pragma unroll
  for (int ut = 0; ut < 4; ++ut) {
    const int u = ut * 16 + l15;
#pragma unroll
    for (int reg = 0; reg < 4; ++reg) {
      size_t idx = ((size_t)(b * 16384 + rowbase + reg)) * U_ + u;
      float x = acc[ut][reg] + out[idx];
      out[idx] = 1.0f / (1.0f + __expf(-x));
    }
  }
#undef LOADC
#undef WRITEC
#undef COMPUTE
#undef BAR
}

// -------------------------------------------------------------------------
extern "C" void kernel_launch(void* const* d_in, const int* in_sizes, int n_in,
                              void* d_out, int out_size, void* d_ws, size_t ws_size,
                              hipStream_t stream) {
  const float* seq   = (const float*)d_in[0];  // (B,N,F)
  const float* graph = (const float*)d_in[1];  // (B,N,N,M)
  const float* ew    = (const float*)d_in[2];  // (F,U)
  const float* vw    = (const float*)d_in[3];  // (F,M,U)
  float* out = (float*)d_out;                  // (B,N,M,U)

  f16* betah = (f16*)d_ws;                     // [B][U][N] fp16 hi = 512 KB
  f16* betal = betah + (size_t)2 * U_ * N_;    // [B][U][N] fp16 lo = 512 KB

  hipLaunchKernelGGL(k_beta,  dim3(256), dim3(256), 0, stream, seq, ew, betah, betal);
  hipLaunchKernelGGL(k_alpha, dim3(512), dim3(256), 0, stream, seq, vw, out);
  hipLaunchKernelGGL(k_main,  dim3(512), dim3(256), 0, stream, graph, betah, betal, out);
}

// Round 2
// 401.327 us; speedup vs baseline: 1.0203x; 1.0203x over previous
//
#include <hip/hip_runtime.h>
#include <cmath>

// (B, N, F_IN, M, U) = (2, 2048, 128, 8, 64)
#define N_ 2048
#define F_ 128
#define M_ 8
#define U_ 64

typedef _Float16 f16;
typedef _Float16 f16x2 __attribute__((ext_vector_type(2)));
typedef _Float16 f16x8 __attribute__((ext_vector_type(8)));
typedef float f32x4 __attribute__((ext_vector_type(4)));

#define BK 32   // K-chunk (j) per stage
#define RS 40   // LDS row stride in fp16 (BK + 8 pad; 80 B, 16-B aligned)
#define NCH (N_ / BK)  // 64 chunks

// -------------------------------------------------------------------------
// k_pre: fused k_beta + k_alpha (independent, both read only seq).
// blocks [0,512):   alpha-role — out[b,n,m,u] = sum_f seq*vw (fp32 pre-act)
// blocks [512,768): beta-role  — beta = seq @ ew, split-fp16 hi/lo,
//                   stored TRANSPOSED [b][u][n] for k_main's B fragments.
// Merging removes one launch and overlaps beta (short) with alpha.
// -------------------------------------------------------------------------
__global__ __launch_bounds__(256) void k_pre(const float* __restrict__ seq,
                                             const float* __restrict__ ew,
                                             const float* __restrict__ vw,
                                             f16* __restrict__ bh,
                                             f16* __restrict__ bl,
                                             float* __restrict__ out) {
  __shared__ float smem[16 * 132];
  const int t = threadIdx.x;

  if (blockIdx.x < 512) {
    // ---- alpha role (identical math to old k_alpha) ----
    const int q    = t & 15;
    const int g    = t >> 4;
    const int r    = g & 7;
    const int mh   = g >> 3;
    const int row0 = blockIdx.x * 8;
    {
      float4 v = *(const float4*)(seq + (size_t)row0 * F_ + t * 4);
      *(float4*)&smem[t * 4] = v;
    }
    __syncthreads();
    float acc[4][4] = {};
    const float* wbase = vw + mh * 4 * 64 + q * 4;
#pragma unroll 4
    for (int f = 0; f < F_; ++f) {
      float s = smem[r * F_ + f];
      const float* wf = wbase + (size_t)f * 512;
#pragma unroll
      for (int mm = 0; mm < 4; ++mm) {
        float4 wv = *(const float4*)(wf + mm * 64);
        acc[mm][0] = fmaf(s, wv.x, acc[mm][0]);
        acc[mm][1] = fmaf(s, wv.y, acc[mm][1]);
        acc[mm][2] = fmaf(s, wv.z, acc[mm][2]);
        acc[mm][3] = fmaf(s, wv.w, acc[mm][3]);
      }
    }
    float* o = out + (size_t)(row0 + r) * 512 + mh * 4 * 64 + q * 4;
#pragma unroll
    for (int mm = 0; mm < 4; ++mm) {
      float4 res;
      res.x = acc[mm][0]; res.y = acc[mm][1];
      res.z = acc[mm][2]; res.w = acc[mm][3];
      *(float4*)(o + mm * 64) = res;
    }
  } else {
    // ---- beta role (identical math to old k_beta) ----
    const int lane = t & 63;
    const int wv   = t >> 6;
    const int row0 = (blockIdx.x - 512) * 16;
#pragma unroll
    for (int k = 0; k < 2; ++k) {
      int id = t + k * 256;
      int r = id >> 5, f4 = id & 31;
      float4 v = *(const float4*)(seq + (size_t)(row0 + r) * F_ + f4 * 4);
      *(float4*)&smem[r * 132 + f4 * 4] = v;
    }
    __syncthreads();
    const int r0 = wv * 4;
    float acc[4] = {0.f, 0.f, 0.f, 0.f};
#pragma unroll 8
    for (int f = 0; f < F_; ++f) {
      float e = ew[f * U_ + lane];
#pragma unroll
      for (int r = 0; r < 4; ++r)
        acc[r] = fmaf(smem[(r0 + r) * 132 + f], e, acc[r]);
    }
#pragma unroll
    for (int r = 0; r < 4; ++r) {
      int row = row0 + r0 + r;
      int b = row >> 11, n = row & (N_ - 1);
      float v = acc[r];
      f16 h = (f16)v;
      f16 l = (f16)(v - (float)h);
      size_t idx = ((size_t)(b * U_ + lane)) * N_ + n;  // [b][u][n]
      bh[idx] = h;
      bl[idx] = l;
    }
  }
}

// -------------------------------------------------------------------------
// k_main v7 (MFMA, no-drain pipeline, 2x2 wave split): per batch,
// C[r=i*8+m][u] = sum_j A[r][j]*B[j][u]; A = graph slice (fp32 -> split
// fp16 hi/lo on the fly), B = split-fp16 beta (k-major from k_pre).
// mfma_f32_16x16x32_f16, 3 MFMA/tile (hi*hi + lo*hi + hi*lo).
//
// v7 change: wave split 1x4 -> 2x2. Wave w owns rows wr*32..+32, cols
// wc*32..+32 (wr=w>>1, wc=w&1): per chunk 4 A-frags + 4 B-frags = 8
// ds_read_b128/wave (was 2+8=10). LDS read serialization drops 480 ->
// 384 cyc/chunk/block, putting LDS (~36 us/CU) under the HBM roof
// (43 us). MFMA count, acc budget, pipeline all unchanged.
//
// Pipeline (v6): raw s_barrier + lgkmcnt(0) only — global prefetch loads
// stay in flight across barriers; two register sets; loads issued BEFORE
// the register-consuming LDS write; tails peeled so no conditional loads
// (a guarded LOADC would force the compiler's waitcnt meet to vmcnt(0)).
//
// Layouts (HW-verified facts): A-frag A[m=lane&15][k=(lane>>4)*8+j],
// B-frag B[k=(lane>>4)*8+j][n=lane&15], C/D col=lane&15,
// row=(lane>>4)*4+reg. LDS row stride RS=40 fp16 -> b128 frag reads at
// baseline rate; staging writes <=2-way (free). HBM floor: 268 MB /
// 6.3 TB/s = 43 us. Grid 512 = 2 blocks/CU, 8 waves/CU.
// -------------------------------------------------------------------------
__global__ __launch_bounds__(256, 2) void k_main(const float* __restrict__ graph,
                                                 const f16* __restrict__ betah,
                                                 const f16* __restrict__ betal,
                                                 float* __restrict__ out) {
  __shared__ f16 Ah[2][64 * RS];
  __shared__ f16 Al[2][64 * RS];
  __shared__ f16 Bh[2][64 * RS];
  __shared__ f16 Bl[2][64 * RS];

  const int t    = threadIdx.x;
  const int w    = t >> 6;
  const int lane = t & 63;
  const int l15  = lane & 15;
  const int quad = lane >> 4;
  const int wr   = w >> 1;        // row-half of the 64x64 tile
  const int wc   = w & 1;         // col-half

  const int bx = blockIdx.x;
  const int b  = bx >> 8;
  const int rb = bx & 255;        // 64-row tile; i0 = rb*8

  // staging decode: A: thread -> (i_loc, j-pair, m-half); B: (u-row, j-part)
  const int iA = t >> 5;          // 0..7
  const int r5 = t & 31;
  const int jp = r5 >> 1;         // 0..15
  const int mh = r5 & 1;          // 0..1
  const int uB = t >> 2;          // 0..63
  const int pB = t & 3;           // 0..3

  const float* gA = graph + ((size_t)(b * N_ + rb * 8 + iA)) * (N_ * M_) + mh * 4;
  const f16* bhp = betah + ((size_t)(b * U_ + uB)) * N_ + pB * 8;
  const f16* blp = betal + ((size_t)(b * U_ + uB)) * N_ + pB * 8;

  f32x4 acc[2][2] = {{f32x4{0.f, 0.f, 0.f, 0.f}, f32x4{0.f, 0.f, 0.f, 0.f}},
                     {f32x4{0.f, 0.f, 0.f, 0.f}, f32x4{0.f, 0.f, 0.f, 0.f}}};

  // two register prefetch sets (S = 0/1)
  float4 ra0_0, ra1_0; uint4 rbh_0, rbl_0;
  float4 ra0_1, ra1_1; uint4 rbh_1, rbl_1;

#define LOADC(c, S)                                                       \
  do {                                                                    \
    const float* g_ = gA + (size_t)((c) * BK + jp * 2) * M_;              \
    ra0_##S = *(const float4*)g_;                                         \
    ra1_##S = *(const float4*)(g_ + M_);                                  \
    rbh_##S = *(const uint4*)(bhp + (c) * BK);                            \
    rbl_##S = *(const uint4*)(blp + (c) * BK);                            \
  } while (0)

#define WRITEC(buf, S)                                                    \
  do {                                                                    \
    float g0s[4] = {ra0_##S.x, ra0_##S.y, ra0_##S.z, ra0_##S.w};          \
    float g1s[4] = {ra1_##S.x, ra1_##S.y, ra1_##S.z, ra1_##S.w};          \
    _Pragma("unroll") for (int mw = 0; mw < 4; ++mw) {                    \
      float g0 = g0s[mw], g1 = g1s[mw];                                   \
      f16 h0 = (f16)g0, h1 = (f16)g1;                                     \
      f16 l0 = (f16)(g0 - (float)h0), l1 = (f16)(g1 - (float)h1);         \
      int r_ = iA * 8 + mh * 4 + mw;                                      \
      f16x2 hv; hv[0] = h0; hv[1] = h1;                                   \
      f16x2 lv; lv[0] = l0; lv[1] = l1;                                   \
      *(f16x2*)&Ah[buf][r_ * RS + jp * 2] = hv;                           \
      *(f16x2*)&Al[buf][r_ * RS + jp * 2] = lv;                           \
    }                                                                     \
    *(uint4*)&Bh[buf][uB * RS + pB * 8] = rbh_##S;                        \
    *(uint4*)&Bl[buf][uB * RS + pB * 8] = rbl_##S;                        \
  } while (0)

#define COMPUTE(buf)                                                      \
  do {                                                                    \
    f16x8 bhf[2], blf[2];                                                 \
    _Pragma("unroll") for (int nt = 0; nt < 2; ++nt) {                    \
      const int bb_ = (wc * 32 + nt * 16 + l15) * RS + quad * 8;          \
      bhf[nt] = *(const f16x8*)&Bh[buf][bb_];                             \
      blf[nt] = *(const f16x8*)&Bl[buf][bb_];                             \
    }                                                                     \
    _Pragma("unroll") for (int mt = 0; mt < 2; ++mt) {                    \
      const int ab_ = (wr * 32 + mt * 16 + l15) * RS + quad * 8;          \
      f16x8 ah = *(const f16x8*)&Ah[buf][ab_];                            \
      f16x8 al = *(const f16x8*)&Al[buf][ab_];                            \
      _Pragma("unroll") for (int nt = 0; nt < 2; ++nt) {                  \
        acc[mt][nt] = __builtin_amdgcn_mfma_f32_16x16x32_f16(ah, bhf[nt], acc[mt][nt], 0, 0, 0); \
        acc[mt][nt] = __builtin_amdgcn_mfma_f32_16x16x32_f16(al, bhf[nt], acc[mt][nt], 0, 0, 0); \
        acc[mt][nt] = __builtin_amdgcn_mfma_f32_16x16x32_f16(ah, blf[nt], acc[mt][nt], 0, 0, 0); \
      }                                                                   \
    }                                                                     \
  } while (0)

// raw barrier: each wave drains its OWN ds traffic (lgkmcnt), NOT vmcnt —
// global prefetch loads stay in flight across the barrier.
#define BAR()                                                             \
  do {                                                                    \
    asm volatile("s_waitcnt lgkmcnt(0)" ::: "memory");                    \
    __builtin_amdgcn_s_barrier();                                         \
    asm volatile("" ::: "memory");                                        \
  } while (0)

  // prologue: buf0 <- chunk0 (one full-latency wait, only here);
  // set1 <- chunk1 stays in flight across the first compute.
  LOADC(0, 0);
  WRITEC(0, 0);
  LOADC(1, 1);
  BAR();

  // steady state: chunks 0..59, NO conditionals -> counted vmcnt waits.
  for (int cc = 0; cc < NCH - 4; cc += 2) {
    COMPUTE(0);                   // chunk cc
    LOADC(cc + 2, 0);             // issue BEFORE consuming set1
    WRITEC(1, 1);                 // buf1 <- chunk cc+1 (counted vmcnt wait)
    BAR();
    COMPUTE(1);                   // chunk cc+1
    LOADC(cc + 3, 1);
    WRITEC(0, 0);                 // buf0 <- chunk cc+2
    BAR();
  }

  // peeled tail: chunks 60..63 (loads 62, 63 issued here; no guards)
  COMPUTE(0);                     // chunk 60
  LOADC(NCH - 2, 0);              // 62
  WRITEC(1, 1);                   // buf1 <- chunk 61
  BAR();
  COMPUTE(1);                     // chunk 61
  LOADC(NCH - 1, 1);              // 63
  WRITEC(0, 0);                   // buf0 <- chunk 62
  BAR();
  COMPUTE(0);                     // chunk 62
  WRITEC(1, 1);                   // buf1 <- chunk 63 (vmcnt(0) once, tail only)
  BAR();
  COMPUTE(1);                     // chunk 63

  // Epilogue: C row = rb*64 + wr*32 + mt*16 + quad*4 + reg,
  //           col u = wc*32 + nt*16 + l15.
  const int rowbase = rb * 64 + wr * 32 + quad * 4;
#pragma unroll
  for (int mt = 0; mt < 2; ++mt) {
#pragma unroll
    for (int nt = 0; nt < 2; ++nt) {
      const int u = wc * 32 + nt * 16 + l15;
#pragma unroll
      for (int reg = 0; reg < 4; ++reg) {
        size_t idx = ((size_t)(b * 16384 + rowbase + mt * 16 + reg)) * U_ + u;
        float x = acc[mt][nt][reg] + out[idx];
        out[idx] = 1.0f / (1.0f + __expf(-x));
      }
    }
  }
#undef LOADC
#undef WRITEC
#undef COMPUTE
#undef BAR
}

// -------------------------------------------------------------------------
extern "C" void kernel_launch(void* const* d_in, const int* in_sizes, int n_in,
                              void* d_out, int out_size, void* d_ws, size_t ws_size,
                              hipStream_t stream) {
  const float* seq   = (const float*)d_in[0];  // (B,N,F)
  const float* graph = (const float*)d_in[1];  // (B,N,N,M)
  const float* ew    = (const float*)d_in[2];  // (F,U)
  const float* vw    = (const float*)d_in[3];  // (F,M,U)
  float* out = (float*)d_out;                  // (B,N,M,U)

  f16* betah = (f16*)d_ws;                     // [B][U][N] fp16 hi = 512 KB
  f16* betal = betah + (size_t)2 * U_ * N_;    // [B][U][N] fp16 lo = 512 KB

  hipLaunchKernelGGL(k_pre,  dim3(768), dim3(256), 0, stream, seq, ew, vw, betah, betal, out);
  hipLaunchKernelGGL(k_main, dim3(512), dim3(256), 0, stream, graph, betah, betal, out);
}

// Round 3
// 397.574 us; speedup vs baseline: 1.0300x; 1.0094x over previous
//
#include <hip/hip_runtime.h>
#include <cmath>

// (B, N, F_IN, M, U) = (2, 2048, 128, 8, 64)
#define N_ 2048
#define F_ 128
#define M_ 8
#define U_ 64

typedef _Float16 f16;
typedef _Float16 f16x2 __attribute__((ext_vector_type(2)));
typedef _Float16 f16x8 __attribute__((ext_vector_type(8)));
typedef float f32x4 __attribute__((ext_vector_type(4)));

#define BK 32   // K-chunk (j) per stage
#define RS 40   // LDS row stride in fp16 (BK + 8 pad; 80 B, 16-B aligned)
#define NCH (N_ / BK)  // 64 chunks

// -------------------------------------------------------------------------
// k_pre: fused beta + alpha (independent, both read only seq).
// blocks [0,512):   alpha-role — out[b,n,m,u] = sum_f seq*vw (fp32 pre-act)
// blocks [512,768): beta-role  — beta = seq @ ew, fp16 hi ONLY (v8: the
//                   beta-lo term is dropped in k_main; see analysis there),
//                   stored TRANSPOSED [b][u][n] for k_main's B fragments.
// -------------------------------------------------------------------------
__global__ __launch_bounds__(256) void k_pre(const float* __restrict__ seq,
                                             const float* __restrict__ ew,
                                             const float* __restrict__ vw,
                                             f16* __restrict__ bh,
                                             float* __restrict__ out) {
  __shared__ float smem[16 * 132];
  const int t = threadIdx.x;

  if (blockIdx.x < 512) {
    // ---- alpha role ----
    const int q    = t & 15;
    const int g    = t >> 4;
    const int r    = g & 7;
    const int mh   = g >> 3;
    const int row0 = blockIdx.x * 8;
    {
      float4 v = *(const float4*)(seq + (size_t)row0 * F_ + t * 4);
      *(float4*)&smem[t * 4] = v;
    }
    __syncthreads();
    float acc[4][4] = {};
    const float* wbase = vw + mh * 4 * 64 + q * 4;
#pragma unroll 4
    for (int f = 0; f < F_; ++f) {
      float s = smem[r * F_ + f];
      const float* wf = wbase + (size_t)f * 512;
#pragma unroll
      for (int mm = 0; mm < 4; ++mm) {
        float4 wv = *(const float4*)(wf + mm * 64);
        acc[mm][0] = fmaf(s, wv.x, acc[mm][0]);
        acc[mm][1] = fmaf(s, wv.y, acc[mm][1]);
        acc[mm][2] = fmaf(s, wv.z, acc[mm][2]);
        acc[mm][3] = fmaf(s, wv.w, acc[mm][3]);
      }
    }
    float* o = out + (size_t)(row0 + r) * 512 + mh * 4 * 64 + q * 4;
#pragma unroll
    for (int mm = 0; mm < 4; ++mm) {
      float4 res;
      res.x = acc[mm][0]; res.y = acc[mm][1];
      res.z = acc[mm][2]; res.w = acc[mm][3];
      *(float4*)(o + mm * 64) = res;
    }
  } else {
    // ---- beta role (hi only; no lo split) ----
    const int lane = t & 63;
    const int wv   = t >> 6;
    const int row0 = (blockIdx.x - 512) * 16;
#pragma unroll
    for (int k = 0; k < 2; ++k) {
      int id = t + k * 256;
      int r = id >> 5, f4 = id & 31;
      float4 v = *(const float4*)(seq + (size_t)(row0 + r) * F_ + f4 * 4);
      *(float4*)&smem[r * 132 + f4 * 4] = v;
    }
    __syncthreads();
    const int r0 = wv * 4;
    float acc[4] = {0.f, 0.f, 0.f, 0.f};
#pragma unroll 8
    for (int f = 0; f < F_; ++f) {
      float e = ew[f * U_ + lane];
#pragma unroll
      for (int r = 0; r < 4; ++r)
        acc[r] = fmaf(smem[(r0 + r) * 132 + f], e, acc[r]);
    }
#pragma unroll
    for (int r = 0; r < 4; ++r) {
      int row = row0 + r0 + r;
      int b = row >> 11, n = row & (N_ - 1);
      size_t idx = ((size_t)(b * U_ + lane)) * N_ + n;  // [b][u][n]
      bh[idx] = (f16)acc[r];
    }
  }
}

// -------------------------------------------------------------------------
// k_main v8 (MFMA, no-drain pipeline, 2x2 wave split, beta-lo DROPPED):
// per batch, C[r=i*8+m][u] = sum_j A[r][j]*B[j][u]; A = graph slice
// (fp32 -> split fp16 hi/lo on the fly), B = fp16 beta (k-major).
// 2 MFMA/tile: ah*bh + al*bh. The dropped gh*bl term contributes
// ~2.2e-3 std pre-act (beta's fp16 ulp scales with |beta|; g rms 0.577;
// sqrt(2048) accumulation) -> ~2.7e-3 added output absmax. The A-side
// lo is KEPT (dropping it would add 4.8e-3 std, 2.2x worse).
//
// v8 savings per chunk: MFMA 12->8, frag reads 8->6 b128/wave, prefetch
// loads 4->3, LDS write streams 3->2 (B single), LDS 40->30 KB, -8 VGPR.
//
// Pipeline (v6): raw s_barrier + lgkmcnt(0) only — global prefetch loads
// stay in flight across barriers; two register sets; loads issued BEFORE
// the register-consuming LDS write; tails peeled so no conditional loads
// (a guarded LOADC would force the compiler's waitcnt meet to vmcnt(0)).
//
// Layouts (HW-verified facts): A-frag A[m=lane&15][k=(lane>>4)*8+j],
// B-frag B[k=(lane>>4)*8+j][n=lane&15], C/D col=lane&15,
// row=(lane>>4)*4+reg. LDS row stride RS=40 fp16 -> b128 frag reads at
// baseline rate; staging writes <=2-way (free). HBM floor: 268 MB /
// 6.3 TB/s = 43 us. Grid 512 = 2 blocks/CU, 8 waves/CU.
// -------------------------------------------------------------------------
__global__ __launch_bounds__(256, 2) void k_main(const float* __restrict__ graph,
                                                 const f16* __restrict__ betah,
                                                 float* __restrict__ out) {
  __shared__ f16 Ah[2][64 * RS];
  __shared__ f16 Al[2][64 * RS];
  __shared__ f16 Bh[2][64 * RS];

  const int t    = threadIdx.x;
  const int w    = t >> 6;
  const int lane = t & 63;
  const int l15  = lane & 15;
  const int quad = lane >> 4;
  const int wr   = w >> 1;        // row-half of the 64x64 tile
  const int wc   = w & 1;         // col-half

  const int bx = blockIdx.x;
  const int b  = bx >> 8;
  const int rb = bx & 255;        // 64-row tile; i0 = rb*8

  // staging decode: A: thread -> (i_loc, j-pair, m-half); B: (u-row, j-part)
  const int iA = t >> 5;          // 0..7
  const int r5 = t & 31;
  const int jp = r5 >> 1;         // 0..15
  const int mh = r5 & 1;          // 0..1
  const int uB = t >> 2;          // 0..63
  const int pB = t & 3;           // 0..3

  const float* gA = graph + ((size_t)(b * N_ + rb * 8 + iA)) * (N_ * M_) + mh * 4;
  const f16* bhp = betah + ((size_t)(b * U_ + uB)) * N_ + pB * 8;

  f32x4 acc[2][2] = {{f32x4{0.f, 0.f, 0.f, 0.f}, f32x4{0.f, 0.f, 0.f, 0.f}},
                     {f32x4{0.f, 0.f, 0.f, 0.f}, f32x4{0.f, 0.f, 0.f, 0.f}}};

  // two register prefetch sets (S = 0/1)
  float4 ra0_0, ra1_0; uint4 rbh_0;
  float4 ra0_1, ra1_1; uint4 rbh_1;

#define LOADC(c, S)                                                       \
  do {                                                                    \
    const float* g_ = gA + (size_t)((c) * BK + jp * 2) * M_;              \
    ra0_##S = *(const float4*)g_;                                         \
    ra1_##S = *(const float4*)(g_ + M_);                                  \
    rbh_##S = *(const uint4*)(bhp + (c) * BK);                            \
  } while (0)

#define WRITEC(buf, S)                                                    \
  do {                                                                    \
    float g0s[4] = {ra0_##S.x, ra0_##S.y, ra0_##S.z, ra0_##S.w};          \
    float g1s[4] = {ra1_##S.x, ra1_##S.y, ra1_##S.z, ra1_##S.w};          \
    _Pragma("unroll") for (int mw = 0; mw < 4; ++mw) {                    \
      float g0 = g0s[mw], g1 = g1s[mw];                                   \
      f16 h0 = (f16)g0, h1 = (f16)g1;                                     \
      f16 l0 = (f16)(g0 - (float)h0), l1 = (f16)(g1 - (float)h1);         \
      int r_ = iA * 8 + mh * 4 + mw;                                      \
      f16x2 hv; hv[0] = h0; hv[1] = h1;                                   \
      f16x2 lv; lv[0] = l0; lv[1] = l1;                                   \
      *(f16x2*)&Ah[buf][r_ * RS + jp * 2] = hv;                           \
      *(f16x2*)&Al[buf][r_ * RS + jp * 2] = lv;                           \
    }                                                                     \
    *(uint4*)&Bh[buf][uB * RS + pB * 8] = rbh_##S;                        \
  } while (0)

#define COMPUTE(buf)                                                      \
  do {                                                                    \
    f16x8 bhf[2];                                                         \
    _Pragma("unroll") for (int nt = 0; nt < 2; ++nt) {                    \
      const int bb_ = (wc * 32 + nt * 16 + l15) * RS + quad * 8;          \
      bhf[nt] = *(const f16x8*)&Bh[buf][bb_];                             \
    }                                                                     \
    _Pragma("unroll") for (int mt = 0; mt < 2; ++mt) {                    \
      const int ab_ = (wr * 32 + mt * 16 + l15) * RS + quad * 8;          \
      f16x8 ah = *(const f16x8*)&Ah[buf][ab_];                            \
      f16x8 al = *(const f16x8*)&Al[buf][ab_];                            \
      _Pragma("unroll") for (int nt = 0; nt < 2; ++nt) {                  \
        acc[mt][nt] = __builtin_amdgcn_mfma_f32_16x16x32_f16(ah, bhf[nt], acc[mt][nt], 0, 0, 0); \
        acc[mt][nt] = __builtin_amdgcn_mfma_f32_16x16x32_f16(al, bhf[nt], acc[mt][nt], 0, 0, 0); \
      }                                                                   \
    }                                                                     \
  } while (0)

// raw barrier: each wave drains its OWN ds traffic (lgkmcnt), NOT vmcnt —
// global prefetch loads stay in flight across the barrier.
#define BAR()                                                             \
  do {                                                                    \
    asm volatile("s_waitcnt lgkmcnt(0)" ::: "memory");                    \
    __builtin_amdgcn_s_barrier();                                         \
    asm volatile("" ::: "memory");                                        \
  } while (0)

  // prologue: buf0 <- chunk0 (one full-latency wait, only here);
  // set1 <- chunk1 stays in flight across the first compute.
  LOADC(0, 0);
  WRITEC(0, 0);
  LOADC(1, 1);
  BAR();

  // steady state: chunks 0..59, NO conditionals -> counted vmcnt waits.
  for (int cc = 0; cc < NCH - 4; cc += 2) {
    COMPUTE(0);                   // chunk cc
    LOADC(cc + 2, 0);             // issue BEFORE consuming set1
    WRITEC(1, 1);                 // buf1 <- chunk cc+1 (counted vmcnt wait)
    BAR();
    COMPUTE(1);                   // chunk cc+1
    LOADC(cc + 3, 1);
    WRITEC(0, 0);                 // buf0 <- chunk cc+2
    BAR();
  }

  // peeled tail: chunks 60..63 (loads 62, 63 issued here; no guards)
  COMPUTE(0);                     // chunk 60
  LOADC(NCH - 2, 0);              // 62
  WRITEC(1, 1);                   // buf1 <- chunk 61
  BAR();
  COMPUTE(1);                     // chunk 61
  LOADC(NCH - 1, 1);              // 63
  WRITEC(0, 0);                   // buf0 <- chunk 62
  BAR();
  COMPUTE(0);                     // chunk 62
  WRITEC(1, 1);                   // buf1 <- chunk 63 (vmcnt(0) once, tail only)
  BAR();
  COMPUTE(1);                     // chunk 63

  // Epilogue: C row = rb*64 + wr*32 + mt*16 + quad*4 + reg,
  //           col u = wc*32 + nt*16 + l15.
  const int rowbase = rb * 64 + wr * 32 + quad * 4;
#pragma unroll
  for (int mt = 0; mt < 2; ++mt) {
#pragma unroll
    for (int nt = 0; nt < 2; ++nt) {
      const int u = wc * 32 + nt * 16 + l15;
#pragma unroll
      for (int reg = 0; reg < 4; ++reg) {
        size_t idx = ((size_t)(b * 16384 + rowbase + mt * 16 + reg)) * U_ + u;
        float x = acc[mt][nt][reg] + out[idx];
        out[idx] = 1.0f / (1.0f + __expf(-x));
      }
    }
  }
#undef LOADC
#undef WRITEC
#undef COMPUTE
#undef BAR
}

// -------------------------------------------------------------------------
extern "C" void kernel_launch(void* const* d_in, const int* in_sizes, int n_in,
                              void* d_out, int out_size, void* d_ws, size_t ws_size,
                              hipStream_t stream) {
  const float* seq   = (const float*)d_in[0];  // (B,N,F)
  const float* graph = (const float*)d_in[1];  // (B,N,N,M)
  const float* ew    = (const float*)d_in[2];  // (F,U)
  const float* vw    = (const float*)d_in[3];  // (F,M,U)
  float* out = (float*)d_out;                  // (B,N,M,U)

  f16* betah = (f16*)d_ws;                     // [B][U][N] fp16 hi = 512 KB

  hipLaunchKernelGGL(k_pre,  dim3(768), dim3(256), 0, stream, seq, ew, vw, betah, out);
  hipLaunchKernelGGL(k_main, dim3(512), dim3(256), 0, stream, graph, betah, out);
}

// Round 4
// 374.683 us; speedup vs baseline: 1.0929x; 1.0611x over previous
//
#include <hip/hip_runtime.h>
#include <cmath>

// (B, N, F_IN, M, U) = (2, 2048, 128, 8, 64)
#define N_ 2048
#define F_ 128
#define M_ 8
#define U_ 64

typedef _Float16 f16;
typedef _Float16 f16x2 __attribute__((ext_vector_type(2)));
typedef _Float16 f16x8 __attribute__((ext_vector_type(8)));
typedef float f32x4 __attribute__((ext_vector_type(4)));

#define BK 32    // K-chunk (j) per stage
#define RS 40    // LDS row stride in fp16 (BK + 8 pad; 80 B, 16-B aligned)
#define RS2 136  // seq_f16 row stride (128 + 8 pad)
#define AS 66    // alpha_lds row stride (64 + 2 pad, fp32)
#define NCH (N_ / BK)  // 64 chunks

// -------------------------------------------------------------------------
// k_pre (v9: beta ONLY — alpha moved into k_main, out is now write-only
// there). beta = seq @ ew, fp16 hi, stored TRANSPOSED [b][u][n] (k-major
// for k_main's B fragments). grid 256, block 256.
// -------------------------------------------------------------------------
__global__ __launch_bounds__(256) void k_pre(const float* __restrict__ seq,
                                             const float* __restrict__ ew,
                                             f16* __restrict__ bh) {
  __shared__ float smem[16 * 132];
  const int t    = threadIdx.x;
  const int lane = t & 63;
  const int wv   = t >> 6;
  const int row0 = blockIdx.x * 16;
#pragma unroll
  for (int k = 0; k < 2; ++k) {
    int id = t + k * 256;
    int r = id >> 5, f4 = id & 31;
    float4 v = *(const float4*)(seq + (size_t)(row0 + r) * F_ + f4 * 4);
    *(float4*)&smem[r * 132 + f4 * 4] = v;
  }
  __syncthreads();
  const int r0 = wv * 4;
  float acc[4] = {0.f, 0.f, 0.f, 0.f};
#pragma unroll 8
  for (int f = 0; f < F_; ++f) {
    float e = ew[f * U_ + lane];
#pragma unroll
    for (int r = 0; r < 4; ++r)
      acc[r] = fmaf(smem[(r0 + r) * 132 + f], e, acc[r]);
  }
#pragma unroll
  for (int r = 0; r < 4; ++r) {
    int row = row0 + r0 + r;
    int b = row >> 11, n = row & (N_ - 1);
    size_t idx = ((size_t)(b * U_ + lane)) * N_ + n;  // [b][u][n]
    bh[idx] = (f16)acc[r];
  }
}

// -------------------------------------------------------------------------
// k_main v9 (MFMA, no-drain pipeline, 2x2 wave split, in-kernel alpha):
// graph term: C[r=i*8+m][u] = sum_j A[r][j]*B[j][u]; A = graph slice
// (fp32 -> split fp16 hi/lo on the fly), B = fp16 beta (k-major);
// 2 MFMA/tile (ah*bh + al*bh; beta-lo dropped, see v8 analysis).
//
// v9 change: alpha computed IN-KERNEL as a tail -> out is WRITE-ONLY.
// The block's alpha tile (8 n x 8 m x 64 u) == its C-tile: 8 per-m GEMMs
// D_m(8pad16 x 64) = seq_f16(16x128, rows 8-15 zeroed) @ vw[:,m,:]
// (128x64, f16 cvt from L2-resident vw). Wave w handles m in {2w, 2w+1}:
// 32 MFMA + 256 L2 dword loads per wave, one-time tail (~1 us,
// overlapped across 2 blocks/CU). Result staged via fp32 alpha_lds
// (16.9 KB) to cross the D-layout (row=i) -> C-layout (row=i*8+m)
// mismatch. f16 on seq/vw adds ~7e-4 pre-act err -> ~2e-4 out (<< 7.8e-3
// current absmax). Saves 16.8 MB k_main fetch + 16.8 MB k_pre write +
// k_pre's 512-block alpha role.
//
// Pipeline (v6): raw s_barrier + lgkmcnt(0) only — global prefetch loads
// stay in flight across barriers; two register sets; loads issued BEFORE
// the register-consuming LDS write; tails peeled so no conditional loads
// (a guarded LOADC would force the compiler's waitcnt meet to vmcnt(0)).
//
// Layouts (HW-verified facts): A-frag A[m=lane&15][k=(lane>>4)*8+j],
// B-frag B[k=(lane>>4)*8+j][n=lane&15], C/D col=lane&15,
// row=(lane>>4)*4+reg. LDS: bufs 30 KB + seq_f16 4.3 KB + alpha 16.9 KB
// = 52 KB -> 2 blocks/CU fits (104 < 160 KB). Grid 512 = 2 blocks/CU.
// HBM floor now: 268 MB graph + 16.8 MB out write = 285 MB ~ 45 us.
// -------------------------------------------------------------------------
__global__ __launch_bounds__(256, 2) void k_main(const float* __restrict__ graph,
                                                 const float* __restrict__ seq,
                                                 const float* __restrict__ vw,
                                                 const f16* __restrict__ betah,
                                                 float* __restrict__ out) {
  __shared__ f16 Ah[2][64 * RS];
  __shared__ f16 Al[2][64 * RS];
  __shared__ f16 Bh[2][64 * RS];
  __shared__ f16 seqh[16 * RS2];
  __shared__ float alds[64 * AS];

  const int t    = threadIdx.x;
  const int w    = t >> 6;
  const int lane = t & 63;
  const int l15  = lane & 15;
  const int quad = lane >> 4;
  const int wr   = w >> 1;        // row-half of the 64x64 tile
  const int wc   = w & 1;         // col-half

  const int bx = blockIdx.x;
  const int b  = bx >> 8;
  const int rb = bx & 255;        // 64-row tile; i0 = rb*8

  // staging decode: A: thread -> (i_loc, j-pair, m-half); B: (u-row, j-part)
  const int iA = t >> 5;          // 0..7
  const int r5 = t & 31;
  const int jp = r5 >> 1;         // 0..15
  const int mh = r5 & 1;          // 0..1
  const int uB = t >> 2;          // 0..63
  const int pB = t & 3;           // 0..3

  const float* gA = graph + ((size_t)(b * N_ + rb * 8 + iA)) * (N_ * M_) + mh * 4;
  const f16* bhp = betah + ((size_t)(b * U_ + uB)) * N_ + pB * 8;

  // ---- seq_f16 staging for the alpha tail (rows 8-15 zeroed) ----
  {
    const int r  = t >> 5;        // 0..7
    const int f4 = (t & 31) * 4;  // 0..124
    float4 v = *(const float4*)(seq + ((size_t)(b * N_ + rb * 8 + r)) * F_ + f4);
    f16x2 p0; p0[0] = (f16)v.x; p0[1] = (f16)v.y;
    f16x2 p1; p1[0] = (f16)v.z; p1[1] = (f16)v.w;
    *(f16x2*)&seqh[r * RS2 + f4]     = p0;
    *(f16x2*)&seqh[r * RS2 + f4 + 2] = p1;
    f16x2 z; z[0] = (f16)0.f; z[1] = (f16)0.f;
    *(f16x2*)&seqh[(r + 8) * RS2 + f4]     = z;
    *(f16x2*)&seqh[(r + 8) * RS2 + f4 + 2] = z;
  }

  f32x4 acc[2][2] = {{f32x4{0.f, 0.f, 0.f, 0.f}, f32x4{0.f, 0.f, 0.f, 0.f}},
                     {f32x4{0.f, 0.f, 0.f, 0.f}, f32x4{0.f, 0.f, 0.f, 0.f}}};

  // two register prefetch sets (S = 0/1)
  float4 ra0_0, ra1_0; uint4 rbh_0;
  float4 ra0_1, ra1_1; uint4 rbh_1;

#define LOADC(c, S)                                                       \
  do {                                                                    \
    const float* g_ = gA + (size_t)((c) * BK + jp * 2) * M_;              \
    ra0_##S = *(const float4*)g_;                                         \
    ra1_##S = *(const float4*)(g_ + M_);                                  \
    rbh_##S = *(const uint4*)(bhp + (c) * BK);                            \
  } while (0)

#define WRITEC(buf, S)                                                    \
  do {                                                                    \
    float g0s[4] = {ra0_##S.x, ra0_##S.y, ra0_##S.z, ra0_##S.w};          \
    float g1s[4] = {ra1_##S.x, ra1_##S.y, ra1_##S.z, ra1_##S.w};          \
    _Pragma("unroll") for (int mw = 0; mw < 4; ++mw) {                    \
      float g0 = g0s[mw], g1 = g1s[mw];                                   \
      f16 h0 = (f16)g0, h1 = (f16)g1;                                     \
      f16 l0 = (f16)(g0 - (float)h0), l1 = (f16)(g1 - (float)h1);         \
      int r_ = iA * 8 + mh * 4 + mw;                                      \
      f16x2 hv; hv[0] = h0; hv[1] = h1;                                   \
      f16x2 lv; lv[0] = l0; lv[1] = l1;                                   \
      *(f16x2*)&Ah[buf][r_ * RS + jp * 2] = hv;                           \
      *(f16x2*)&Al[buf][r_ * RS + jp * 2] = lv;                           \
    }                                                                     \
    *(uint4*)&Bh[buf][uB * RS + pB * 8] = rbh_##S;                        \
  } while (0)

#define COMPUTE(buf)                                                      \
  do {                                                                    \
    f16x8 bhf[2];                                                         \
    _Pragma("unroll") for (int nt = 0; nt < 2; ++nt) {                    \
      const int bb_ = (wc * 32 + nt * 16 + l15) * RS + quad * 8;          \
      bhf[nt] = *(const f16x8*)&Bh[buf][bb_];                             \
    }                                                                     \
    _Pragma("unroll") for (int mt = 0; mt < 2; ++mt) {                    \
      const int ab_ = (wr * 32 + mt * 16 + l15) * RS + quad * 8;          \
      f16x8 ah = *(const f16x8*)&Ah[buf][ab_];                            \
      f16x8 al = *(const f16x8*)&Al[buf][ab_];                            \
      _Pragma("unroll") for (int nt = 0; nt < 2; ++nt) {                  \
        acc[mt][nt] = __builtin_amdgcn_mfma_f32_16x16x32_f16(ah, bhf[nt], acc[mt][nt], 0, 0, 0); \
        acc[mt][nt] = __builtin_amdgcn_mfma_f32_16x16x32_f16(al, bhf[nt], acc[mt][nt], 0, 0, 0); \
      }                                                                   \
    }                                                                     \
  } while (0)

// raw barrier: each wave drains its OWN ds traffic (lgkmcnt), NOT vmcnt —
// global prefetch loads stay in flight across the barrier.
#define BAR()                                                             \
  do {                                                                    \
    asm volatile("s_waitcnt lgkmcnt(0)" ::: "memory");                    \
    __builtin_amdgcn_s_barrier();                                         \
    asm volatile("" ::: "memory");                                        \
  } while (0)

  // prologue: buf0 <- chunk0 (one full-latency wait, only here);
  // set1 <- chunk1 stays in flight across the first compute.
  LOADC(0, 0);
  WRITEC(0, 0);
  LOADC(1, 1);
  BAR();

  // steady state: chunks 0..59, NO conditionals -> counted vmcnt waits.
  for (int cc = 0; cc < NCH - 4; cc += 2) {
    COMPUTE(0);                   // chunk cc
    LOADC(cc + 2, 0);             // issue BEFORE consuming set1
    WRITEC(1, 1);                 // buf1 <- chunk cc+1 (counted vmcnt wait)
    BAR();
    COMPUTE(1);                   // chunk cc+1
    LOADC(cc + 3, 1);
    WRITEC(0, 0);                 // buf0 <- chunk cc+2
    BAR();
  }

  // peeled tail: chunks 60..63 (loads 62, 63 issued here; no guards)
  COMPUTE(0);                     // chunk 60
  LOADC(NCH - 2, 0);              // 62
  WRITEC(1, 1);                   // buf1 <- chunk 61
  BAR();
  COMPUTE(1);                     // chunk 61
  LOADC(NCH - 1, 1);              // 63
  WRITEC(0, 0);                   // buf0 <- chunk 62
  BAR();
  COMPUTE(0);                     // chunk 62
  WRITEC(1, 1);                   // buf1 <- chunk 63 (vmcnt(0) once, tail only)
  BAR();
  COMPUTE(1);                     // chunk 63

  // ---- alpha tail: wave w computes m in {2w, 2w+1} ----
  // D_m[i][u] = sum_f seqh[i][f] * vw[f][m][u]; A-frag from seqh (LDS),
  // B-frag: 8 scattered L2 dwords -> f16. D row=quad*4+reg=i (valid i<8
  // -> quad<2), col=l15=u_sub. Accumulate over ks, stage via alds.
  {
    f32x4 acca[2][4] = {{f32x4{0.f,0.f,0.f,0.f}, f32x4{0.f,0.f,0.f,0.f},
                         f32x4{0.f,0.f,0.f,0.f}, f32x4{0.f,0.f,0.f,0.f}},
                        {f32x4{0.f,0.f,0.f,0.f}, f32x4{0.f,0.f,0.f,0.f},
                         f32x4{0.f,0.f,0.f,0.f}, f32x4{0.f,0.f,0.f,0.f}}};
    const int m0 = w * 2;
#pragma unroll
    for (int ks = 0; ks < 4; ++ks) {
      f16x8 af = *(const f16x8*)&seqh[l15 * RS2 + ks * 32 + quad * 8];
#pragma unroll
      for (int mi = 0; mi < 2; ++mi) {
        const float* vwp = vw + (size_t)(ks * 32 + quad * 8) * 512 + (m0 + mi) * 64 + l15;
#pragma unroll
        for (int nt2 = 0; nt2 < 4; ++nt2) {
          f16x8 bf;
#pragma unroll
          for (int j = 0; j < 8; ++j)
            bf[j] = (f16)vwp[(size_t)j * 512 + nt2 * 16];
          acca[mi][nt2] = __builtin_amdgcn_mfma_f32_16x16x32_f16(af, bf, acca[mi][nt2], 0, 0, 0);
        }
      }
    }
    if (quad < 2) {
#pragma unroll
      for (int mi = 0; mi < 2; ++mi)
#pragma unroll
        for (int nt2 = 0; nt2 < 4; ++nt2)
#pragma unroll
          for (int reg = 0; reg < 4; ++reg)
            alds[((quad * 4 + reg) * 8 + m0 + mi) * AS + nt2 * 16 + l15] = acca[mi][nt2][reg];
    }
  }
  BAR();

  // Epilogue: C row = rb*64 + wr*32 + mt*16 + quad*4 + reg,
  //           col u = wc*32 + nt*16 + l15. out is WRITE-ONLY.
  const int rowbase = rb * 64 + wr * 32 + quad * 4;
#pragma unroll
  for (int mt = 0; mt < 2; ++mt) {
#pragma unroll
    for (int nt = 0; nt < 2; ++nt) {
      const int u = wc * 32 + nt * 16 + l15;
#pragma unroll
      for (int reg = 0; reg < 4; ++reg) {
        const int lrow = wr * 32 + mt * 16 + quad * 4 + reg;
        size_t idx = ((size_t)(b * 16384 + rowbase + mt * 16 + reg)) * U_ + u;
        float x = acc[mt][nt][reg] + alds[lrow * AS + u];
        out[idx] = 1.0f / (1.0f + __expf(-x));
      }
    }
  }
#undef LOADC
#undef WRITEC
#undef COMPUTE
#undef BAR
}

// -------------------------------------------------------------------------
extern "C" void kernel_launch(void* const* d_in, const int* in_sizes, int n_in,
                              void* d_out, int out_size, void* d_ws, size_t ws_size,
                              hipStream_t stream) {
  const float* seq   = (const float*)d_in[0];  // (B,N,F)
  const float* graph = (const float*)d_in[1];  // (B,N,N,M)
  const float* ew    = (const float*)d_in[2];  // (F,U)
  const float* vw    = (const float*)d_in[3];  // (F,M,U)
  float* out = (float*)d_out;                  // (B,N,M,U)

  f16* betah = (f16*)d_ws;                     // [B][U][N] fp16 hi = 512 KB

  hipLaunchKernelGGL(k_pre,  dim3(256), dim3(256), 0, stream, seq, ew, betah);
  hipLaunchKernelGGL(k_main, dim3(512), dim3(256), 0, stream, graph, seq, vw, betah, out);
}